// Round 12
// baseline (55.266 us; speedup 1.0000x reference)
//
#include <hip/hip_runtime.h>
#include <hip/hip_bf16.h>

constexpr int B   = 8;
constexpr int N   = 1024;
constexpr int DIN = 128;
constexpr int H   = 8;
constexpr int D   = 16;
constexpr int HD  = 128;   // H*D
constexpr int TI  = 16;    // i-rows per k_attn wave (MFMA M)

#define LOG2E 1.4426950408889634f
#define TCLAMP 30.0f       // never binds on real data (|s·log2e| < ~5)

typedef __attribute__((ext_vector_type(8))) short bf16x8;  // MFMA A/B frag
typedef __attribute__((ext_vector_type(4))) float f32x4;   // MFMA C/D frag

__device__ inline float fast_exp2(float x) {
#if __has_builtin(__builtin_amdgcn_exp2f)
    return __builtin_amdgcn_exp2f(x);
#else
    return exp2f(x);
#endif
}

// ---------------------------------------------------------------------------
// Pack adj -> bitmask bm[row][32] u32. Zero LDS, minimal VGPR -> full
// occupancy; one coalesced streaming pass over the 32 MB adj (unavoidable
// roofline traffic, paid here where 32 waves/CU hide the latency).
// ---------------------------------------------------------------------------
__global__ __launch_bounds__(256) void k_pack(const int* __restrict__ adj,
                                              unsigned int* __restrict__ bm)
{
    const size_t g = (size_t)blockIdx.x * 256 + threadIdx.x;
    const unsigned long long m = __ballot(adj[g] != 0);
    const int l = threadIdx.x & 63;
    if (l == 0)  bm[g >> 5] = (unsigned int)m;
    if (l == 32) bm[g >> 5] = (unsigned int)(m >> 32);
}

// ---------------------------------------------------------------------------
// Kernel 1: MFMA projection. Block = 32 rows (grid 256 = all CUs), 256 thr.
//   Wh = h @ W (bf16 MFMA, f32 acc) -> WhT bf16 [b][c][n]
//   tI/tJ[b][h][n] = (Wh . a_src/dst) * log2e, clamped
// ---------------------------------------------------------------------------
__global__ __launch_bounds__(256) void k_proj(
    const float* __restrict__ hsrc,
    const float* __restrict__ W,
    const float* __restrict__ a,
    __hip_bfloat16* __restrict__ WhT,  // [B][HD][N]
    float* __restrict__ tI,            // [B][H][N]
    float* __restrict__ tJ)            // [B][H][N]
{
    const int row0 = blockIdx.x * 32;    // global row (b*N+n)
    const int b    = row0 >> 10;
    const int n0   = row0 & (N - 1);
    const int t    = threadIdx.x;
    const int lane = t & 63, wave = t >> 6;
    const int mn   = lane & 15, kg = lane >> 4;

    __shared__ __align__(16) __hip_bfloat16 hA[32][136];   // [row][k]
    __shared__ __align__(16) __hip_bfloat16 Wt[128][136];  // [col][k]

    // stage h-tile (32x128 f32 -> bf16)
    {
        const float4* hf = reinterpret_cast<const float4*>(hsrc + (size_t)row0 * DIN);
        #pragma unroll
        for (int u = 0; u < 4; ++u) {
            const int idx = t + u * 256;          // float4 index
            const float4 v = hf[idx];
            const int r = idx >> 5, c4 = (idx & 31) * 4;
            hA[r][c4]     = __float2bfloat16(v.x);
            hA[r][c4 + 1] = __float2bfloat16(v.y);
            hA[r][c4 + 2] = __float2bfloat16(v.z);
            hA[r][c4 + 3] = __float2bfloat16(v.w);
        }
    }
    // stage W transposed (128x128 f32 [k][c] -> bf16 [c][k])
    {
        const float4* wf = reinterpret_cast<const float4*>(W);
        #pragma unroll
        for (int u = 0; u < 16; ++u) {
            const int idx = t + u * 256;
            const float4 v = wf[idx];
            const int k = idx >> 5, c0 = (idx & 31) * 4;
            Wt[c0][k]     = __float2bfloat16(v.x);
            Wt[c0 + 1][k] = __float2bfloat16(v.y);
            Wt[c0 + 2][k] = __float2bfloat16(v.z);
            Wt[c0 + 3][k] = __float2bfloat16(v.w);
        }
    }
    __syncthreads();

    const int lr0 = (wave >> 1) * 16;       // row offset of this wave
    const int ch  = wave & 1;               // col half (64 cols)
    f32x4 acc[4];
    #pragma unroll
    for (int f = 0; f < 4; ++f) acc[f] = (f32x4){0.f, 0.f, 0.f, 0.f};

    #pragma unroll
    for (int kk = 0; kk < 4; ++kk) {
        const bf16x8 af = *reinterpret_cast<const bf16x8*>(
            &hA[lr0 + mn][kk * 32 + kg * 8]);
        #pragma unroll
        for (int f = 0; f < 4; ++f) {
            const bf16x8 bf = *reinterpret_cast<const bf16x8*>(
                &Wt[ch * 64 + f * 16 + mn][kk * 32 + kg * 8]);
            acc[f] = __builtin_amdgcn_mfma_f32_16x16x32_bf16(af, bf, acc[f], 0, 0, 0);
        }
    }

    // epilogue: WhT store + tI/tJ shuffle-reduce (head = ch*4+f, d = mn)
    #pragma unroll
    for (int f = 0; f < 4; ++f) {
        const int hh = ch * 4 + f;
        const float as = a[hh * 32 + mn];       // a[h][d]
        const float ad = a[hh * 32 + 16 + mn];  // a[h][D+d]
        #pragma unroll
        for (int r = 0; r < 4; ++r) {
            const int n = n0 + lr0 + kg * 4 + r;
            WhT[((size_t)(b * HD + ch * 64 + f * 16 + mn)) * N + n] =
                __float2bfloat16(acc[f][r]);
            float vi = acc[f][r] * as;
            float vj = acc[f][r] * ad;
            #pragma unroll
            for (int m = 1; m < 16; m <<= 1) {
                vi += __shfl_xor(vi, m);
                vj += __shfl_xor(vj, m);
            }
            if (mn == 0) {
                tI[((size_t)(b * H + hh)) * N + n] = fminf(vi * LOG2E, TCLAMP);
                tJ[((size_t)(b * H + hh)) * N + n] = fminf(vj * LOG2E, TCLAMP);
            }
        }
    }
}

// ---------------------------------------------------------------------------
// Kernel 2: fused attention — barrier-free, LDS-free, 4-step-batched loads.
// Block = 256 thr = 4 waves = 4 heads; blockIdx.z = head half.
// Lane (mn,kg) owns row i0+mn; builds A-frag scores in registers
// (k = s*32+kg*8+e), matching the MFMA A layout.
// Outer loop (8 iters): load 1 uint4 mask + 8 float4 tj + 4 b128 WhT into
// named register arrays, THEN compute 4 steps (8 lrelu+exp2 each,
// 2 MFMAs per step: accO += P x WhT, accD += P x 1). out = accO/accD.
// ---------------------------------------------------------------------------
__global__ __launch_bounds__(256, 4) void k_attn(
    const unsigned int*   __restrict__ bm,     // [B*N][32] u32
    const __hip_bfloat16* __restrict__ WhT,    // [B][HD][N]
    const float*          __restrict__ tI,     // [B][H][N]
    const float*          __restrict__ tJ,     // [B][H][N]
    float*                __restrict__ out)    // [B][N][HD]
{
    const int b    = blockIdx.y;
    const int i0   = blockIdx.x * TI;
    const int lane = threadIdx.x & 63;
    const int h    = blockIdx.z * 4 + (threadIdx.x >> 6);   // head
    const int mn   = lane & 15, kg = lane >> 4;
    const int row  = i0 + mn;

    const float Arow = tI[((size_t)(b * H + h)) * N + row];
    const float* tjrow = tJ + ((size_t)(b * H + h)) * N + kg * 8;
    const __hip_bfloat16* wrow =
        WhT + ((size_t)(b * HD + h * 16 + mn)) * N + kg * 8;
    const uint4* mrow = reinterpret_cast<const uint4*>(
        bm + ((size_t)(b * N) + row) * 32);

    f32x4 accO = {0.f, 0.f, 0.f, 0.f};
    f32x4 accD = {0.f, 0.f, 0.f, 0.f};
    bf16x8 ones;
    #pragma unroll
    for (int e = 0; e < 8; ++e) ones[e] = (short)0x3F80;   // bf16 1.0

    for (int sq = 0; sq < 8; ++sq) {         // 4 j-steps (128 j's) per iter
        const int j0 = sq * 128;

        // ---- issue ALL loads for this iter (named regs, statically indexed)
        const uint4 mv4 = mrow[sq];
        float4 ta[4], tb[4]; bf16x8 wv[4];
        #pragma unroll
        for (int q = 0; q < 4; ++q) {
            ta[q] = *reinterpret_cast<const float4*>(tjrow + j0 + q * 32);
            tb[q] = *reinterpret_cast<const float4*>(tjrow + j0 + q * 32 + 4);
            wv[q] = *reinterpret_cast<const bf16x8*>(wrow + j0 + q * 32);
        }
        const unsigned int mvq[4] = {mv4.x, mv4.y, mv4.z, mv4.w};

        // ---- compute 4 steps ----
        #pragma unroll
        for (int q = 0; q < 4; ++q) {
            const unsigned int m8 = (mvq[q] >> (kg * 8)) & 0xFFu;
            const float tv[8] = {ta[q].x, ta[q].y, ta[q].z, ta[q].w,
                                 tb[q].x, tb[q].y, tb[q].z, tb[q].w};
            bf16x8 af;
            #pragma unroll
            for (int e = 0; e < 8; ++e) {
                const float x = Arow + tv[e];
                float sc = fmaxf(x, 0.2f * x);
                sc = ((m8 >> e) & 1u) ? sc : -1.0e30f;
                af[e] = (short)__bfloat16_as_ushort(
                    __float2bfloat16(fast_exp2(sc)));
            }
            accO = __builtin_amdgcn_mfma_f32_16x16x32_bf16(af, wv[q], accO, 0, 0, 0);
            accD = __builtin_amdgcn_mfma_f32_16x16x32_bf16(af, ones, accD, 0, 0, 0);
        }
    }

    // ---- normalize + store: C layout col=lane&15, row=(lane>>4)*4+reg ----
    #pragma unroll
    for (int r = 0; r < 4; ++r) {
        out[((size_t)(b * N) + i0 + kg * 4 + r) * HD + h * 16 + mn] =
            accO[r] / accD[r];
    }
}

// ---------------------------------------------------------------------------
extern "C" void kernel_launch(void* const* d_in, const int* in_sizes, int n_in,
                              void* d_out, int out_size, void* d_ws, size_t ws_size,
                              hipStream_t stream)
{
    const float* h   = (const float*)d_in[0];   // f32 (proven R3/R5)
    const int*   adj = (const int*)d_in[1];
    const float* W   = (const float*)d_in[2];
    const float* a   = (const float*)d_in[3];
    float* out = (float*)d_out;

    float* ws = (float*)d_ws;
    float* tI = ws;                              // B*H*N f32 (256 KB)
    float* tJ = ws + (size_t)B * H * N;          // B*H*N f32 (256 KB)
    __hip_bfloat16* WhT = (__hip_bfloat16*)(ws + (size_t)2 * B * H * N); // 2 MB
    unsigned int* bm = (unsigned int*)((char*)WhT +
                       (size_t)B * N * HD * sizeof(__hip_bfloat16));     // 1 MB

    k_pack<<<dim3((B * N * N) / 256), dim3(256), 0, stream>>>(adj, bm);
    k_proj<<<dim3(B * N / 32), dim3(256), 0, stream>>>(h, W, a, WhT, tI, tJ);
    k_attn<<<dim3(N / TI, B, 2), dim3(256), 0, stream>>>(bm, WhT, tI, tJ, out);
}

// Round 13
// 55.102 us; speedup vs baseline: 1.0030x; 1.0030x over previous
//
#include <hip/hip_runtime.h>
#include <hip/hip_bf16.h>

constexpr int B   = 8;
constexpr int N   = 1024;
constexpr int DIN = 128;
constexpr int H   = 8;
constexpr int D   = 16;
constexpr int HD  = 128;   // H*D
constexpr int TI  = 16;    // i-rows per k_attn block (MFMA M)

#define LOG2E 1.4426950408889634f
#define TCLAMP 30.0f       // never binds on real data (|s·log2e| < ~5)

typedef __attribute__((ext_vector_type(8))) short bf16x8;  // MFMA A/B frag
typedef __attribute__((ext_vector_type(4))) float f32x4;   // MFMA C/D frag

__device__ inline float fast_exp2(float x) {
#if __has_builtin(__builtin_amdgcn_exp2f)
    return __builtin_amdgcn_exp2f(x);
#else
    return exp2f(x);
#endif
}

// ---------------------------------------------------------------------------
// Kernel 1: MFMA projection. Block = 16 rows, grid 512 (2 blocks/CU), 256 thr.
//   Wh = h @ W (bf16 MFMA, f32 acc) -> WhT bf16 [b][c][n]
//   tI/tJ[b][h][n] = (Wh . a_src/dst) * log2e, clamped
// Wave w: all 16 rows x cols [w*32, w*32+32) (2 MFMA col-frags).
// ---------------------------------------------------------------------------
__global__ __launch_bounds__(256) void k_proj(
    const float* __restrict__ hsrc,
    const float* __restrict__ W,
    const float* __restrict__ a,
    __hip_bfloat16* __restrict__ WhT,  // [B][HD][N]
    float* __restrict__ tI,            // [B][H][N]
    float* __restrict__ tJ)            // [B][H][N]
{
    const int row0 = blockIdx.x * 16;    // global row (b*N+n)
    const int b    = row0 >> 10;
    const int n0   = row0 & (N - 1);
    const int t    = threadIdx.x;
    const int lane = t & 63, wave = t >> 6;
    const int mn   = lane & 15, kg = lane >> 4;

    __shared__ __align__(16) __hip_bfloat16 hA[16][136];   // [row][k]
    __shared__ __align__(16) __hip_bfloat16 Wt[128][136];  // [col][k]

    // stage h-tile (16x128 f32 -> bf16)
    {
        const float4* hf = reinterpret_cast<const float4*>(hsrc + (size_t)row0 * DIN);
        #pragma unroll
        for (int u = 0; u < 2; ++u) {
            const int idx = t + u * 256;          // float4 index
            const float4 v = hf[idx];
            const int r = idx >> 5, c4 = (idx & 31) * 4;
            hA[r][c4]     = __float2bfloat16(v.x);
            hA[r][c4 + 1] = __float2bfloat16(v.y);
            hA[r][c4 + 2] = __float2bfloat16(v.z);
            hA[r][c4 + 3] = __float2bfloat16(v.w);
        }
    }
    // stage W transposed (128x128 f32 [k][c] -> bf16 [c][k])
    {
        const float4* wf = reinterpret_cast<const float4*>(W);
        #pragma unroll
        for (int u = 0; u < 16; ++u) {
            const int idx = t + u * 256;
            const float4 v = wf[idx];
            const int k = idx >> 5, c0 = (idx & 31) * 4;
            Wt[c0][k]     = __float2bfloat16(v.x);
            Wt[c0 + 1][k] = __float2bfloat16(v.y);
            Wt[c0 + 2][k] = __float2bfloat16(v.z);
            Wt[c0 + 3][k] = __float2bfloat16(v.w);
        }
    }
    __syncthreads();

    f32x4 acc[2];
    acc[0] = (f32x4){0.f, 0.f, 0.f, 0.f};
    acc[1] = (f32x4){0.f, 0.f, 0.f, 0.f};

    #pragma unroll
    for (int kk = 0; kk < 4; ++kk) {
        const bf16x8 af = *reinterpret_cast<const bf16x8*>(
            &hA[mn][kk * 32 + kg * 8]);
        #pragma unroll
        for (int f = 0; f < 2; ++f) {
            const int F = wave * 2 + f;           // col-frag = head
            const bf16x8 bfr = *reinterpret_cast<const bf16x8*>(
                &Wt[F * 16 + mn][kk * 32 + kg * 8]);
            acc[f] = __builtin_amdgcn_mfma_f32_16x16x32_bf16(af, bfr, acc[f], 0, 0, 0);
        }
    }

    // epilogue: WhT store + tI/tJ shuffle-reduce (head = F, d = mn)
    #pragma unroll
    for (int f = 0; f < 2; ++f) {
        const int F = wave * 2 + f;
        const float as = a[F * 32 + mn];       // a[h][d]
        const float ad = a[F * 32 + 16 + mn];  // a[h][D+d]
        #pragma unroll
        for (int r = 0; r < 4; ++r) {
            const int n = n0 + kg * 4 + r;
            WhT[((size_t)(b * HD + F * 16 + mn)) * N + n] =
                __float2bfloat16(acc[f][r]);
            float vi = acc[f][r] * as;
            float vj = acc[f][r] * ad;
            #pragma unroll
            for (int m = 1; m < 16; m <<= 1) {
                vi += __shfl_xor(vi, m);
                vj += __shfl_xor(vj, m);
            }
            if (mn == 0) {
                tI[((size_t)(b * H + F)) * N + n] = fminf(vi * LOG2E, TCLAMP);
                tJ[((size_t)(b * H + F)) * N + n] = fminf(vj * LOG2E, TCLAMP);
            }
        }
    }
}

// ---------------------------------------------------------------------------
// Kernel 2: fused attention with inline adj-pack prologue.
// Block = 512 thr = 8 waves = 8 heads, 16 i-rows; grid (64, 8) = 2 blocks/CU.
// Prologue: wave w ballots rows {2w, 2w+1} of adj (16 coalesced 256B reads
// per row) into LDS m2[word][row] (2 KB). One barrier. adj read exactly once.
// Main loop (8 iters x 128 j): load 4 mask words (LDS, broadcast) + 8 float4
// tj + 4 b128 WhT into named regs, then 4 steps of (8 lrelu+exp2 -> A-frag,
// accO += P x WhT, accD += P x 1). out = accO/accD (softmax shift-invariant,
// no max needed; scores clamped in k_proj).
// ---------------------------------------------------------------------------
__global__ __launch_bounds__(512, 4) void k_attn(
    const int*            __restrict__ adj,    // [B][N][N]
    const __hip_bfloat16* __restrict__ WhT,    // [B][HD][N]
    const float*          __restrict__ tI,     // [B][H][N]
    const float*          __restrict__ tJ,     // [B][H][N]
    float*                __restrict__ out)    // [B][N][HD]
{
    const int b    = blockIdx.y;
    const int i0   = blockIdx.x * TI;
    const int t    = threadIdx.x;
    const int lane = t & 63, h = t >> 6;       // wave = head
    const int mn   = lane & 15, kg = lane >> 4;

    __shared__ unsigned int m2[32][16];        // [word s][row mn]

    // ---- pack prologue: wave h packs rows 2h, 2h+1 ----
    {
        const int* ar = adj + ((size_t)(b * N) + i0 + 2 * h) * N + lane;
        #pragma unroll
        for (int rr = 0; rr < 2; ++rr) {
            #pragma unroll
            for (int tt = 0; tt < 16; ++tt) {
                const int v = ar[rr * N + tt * 64];
                const unsigned long long mm = __ballot(v != 0);
                if (lane == 0)
                    m2[2 * tt][2 * h + rr] = (unsigned int)mm;
                if (lane == 32)
                    m2[2 * tt + 1][2 * h + rr] = (unsigned int)(mm >> 32);
            }
        }
    }
    __syncthreads();

    const float Arow = tI[((size_t)(b * H + h)) * N + i0 + mn];
    const float* tjrow = tJ + ((size_t)(b * H + h)) * N + kg * 8;
    const __hip_bfloat16* wrow =
        WhT + ((size_t)(b * HD + h * 16 + mn)) * N + kg * 8;

    f32x4 accO = {0.f, 0.f, 0.f, 0.f};
    f32x4 accD = {0.f, 0.f, 0.f, 0.f};
    bf16x8 ones;
    #pragma unroll
    for (int e = 0; e < 8; ++e) ones[e] = (short)0x3F80;   // bf16 1.0

    for (int sq = 0; sq < 8; ++sq) {         // 4 j-steps (128 j's) per iter
        const int j0 = sq * 128;

        // ---- issue ALL loads for this iter (named regs, statically indexed)
        unsigned int mvq[4];
        #pragma unroll
        for (int q = 0; q < 4; ++q) mvq[q] = m2[sq * 4 + q][mn];
        float4 ta[4], tb[4]; bf16x8 wv[4];
        #pragma unroll
        for (int q = 0; q < 4; ++q) {
            ta[q] = *reinterpret_cast<const float4*>(tjrow + j0 + q * 32);
            tb[q] = *reinterpret_cast<const float4*>(tjrow + j0 + q * 32 + 4);
            wv[q] = *reinterpret_cast<const bf16x8*>(wrow + j0 + q * 32);
        }

        // ---- compute 4 steps ----
        #pragma unroll
        for (int q = 0; q < 4; ++q) {
            const unsigned int m8 = (mvq[q] >> (kg * 8)) & 0xFFu;
            const float tv[8] = {ta[q].x, ta[q].y, ta[q].z, ta[q].w,
                                 tb[q].x, tb[q].y, tb[q].z, tb[q].w};
            bf16x8 af;
            #pragma unroll
            for (int e = 0; e < 8; ++e) {
                const float x = Arow + tv[e];
                float sc = fmaxf(x, 0.2f * x);
                sc = ((m8 >> e) & 1u) ? sc : -1.0e30f;
                af[e] = (short)__bfloat16_as_ushort(
                    __float2bfloat16(fast_exp2(sc)));
            }
            accO = __builtin_amdgcn_mfma_f32_16x16x32_bf16(af, wv[q], accO, 0, 0, 0);
            accD = __builtin_amdgcn_mfma_f32_16x16x32_bf16(af, ones, accD, 0, 0, 0);
        }
    }

    // ---- normalize + store: C layout col=lane&15, row=(lane>>4)*4+reg ----
    #pragma unroll
    for (int r = 0; r < 4; ++r) {
        out[((size_t)(b * N) + i0 + kg * 4 + r) * HD + h * 16 + mn] =
            accO[r] / accD[r];
    }
}

// ---------------------------------------------------------------------------
extern "C" void kernel_launch(void* const* d_in, const int* in_sizes, int n_in,
                              void* d_out, int out_size, void* d_ws, size_t ws_size,
                              hipStream_t stream)
{
    const float* h   = (const float*)d_in[0];   // f32 (proven R3/R5)
    const int*   adj = (const int*)d_in[1];
    const float* W   = (const float*)d_in[2];
    const float* a   = (const float*)d_in[3];
    float* out = (float*)d_out;

    float* ws = (float*)d_ws;
    float* tI = ws;                              // B*H*N f32 (256 KB)
    float* tJ = ws + (size_t)B * H * N;          // B*H*N f32 (256 KB)
    __hip_bfloat16* WhT = (__hip_bfloat16*)(ws + (size_t)2 * B * H * N); // 2 MB

    k_proj<<<dim3(B * N / 16), dim3(256), 0, stream>>>(h, W, a, WhT, tI, tJ);
    k_attn<<<dim3(N / TI, B), dim3(512), 0, stream>>>(adj, WhT, tI, tJ, out);
}

// Round 14
// 52.820 us; speedup vs baseline: 1.0463x; 1.0432x over previous
//
#include <hip/hip_runtime.h>
#include <hip/hip_bf16.h>

constexpr int B   = 8;
constexpr int N   = 1024;
constexpr int DIN = 128;
constexpr int H   = 8;
constexpr int D   = 16;
constexpr int HD  = 128;   // H*D
constexpr int TI  = 16;    // i-rows per k_attn block (MFMA M)

#define LOG2E 1.4426950408889634f
#define TCLAMP 30.0f       // never binds on real data (|s·log2e| < ~5)

typedef __attribute__((ext_vector_type(8))) short bf16x8;  // MFMA A/B frag
typedef __attribute__((ext_vector_type(4))) float f32x4;   // MFMA C/D frag

__device__ inline float fast_exp2(float x) {
#if __has_builtin(__builtin_amdgcn_exp2f)
    return __builtin_amdgcn_exp2f(x);
#else
    return exp2f(x);
#endif
}

// ---------------------------------------------------------------------------
// Pack adj -> bitmask bm[row][32] u32. One row per wave: 16 independent
// coalesced 256B loads (deep ILP), 32 contiguous mask words stored per row.
// ---------------------------------------------------------------------------
__global__ __launch_bounds__(256) void k_pack(const int* __restrict__ adj,
                                              unsigned int* __restrict__ bm)
{
    const int lane = threadIdx.x & 63;
    const size_t row = (size_t)blockIdx.x * 4 + (threadIdx.x >> 6);
    const int* ar = adj + row * N + lane;
    unsigned int* dst = bm + row * 32;
    #pragma unroll
    for (int tt = 0; tt < 16; ++tt) {
        const unsigned long long m = __ballot(ar[tt * 64] != 0);
        if (lane == 0)  dst[2 * tt]     = (unsigned int)m;
        if (lane == 32) dst[2 * tt + 1] = (unsigned int)(m >> 32);
    }
}

// ---------------------------------------------------------------------------
// Kernel 1: MFMA projection. Block = 16 rows, grid 512 (2 blocks/CU), 256 thr.
//   Wh = h @ W (bf16 MFMA, f32 acc) -> WhT bf16 [b][c][n]
//   tI/tJ[b][h][n] = (Wh . a_src/dst) * log2e, clamped
// ---------------------------------------------------------------------------
__global__ __launch_bounds__(256) void k_proj(
    const float* __restrict__ hsrc,
    const float* __restrict__ W,
    const float* __restrict__ a,
    __hip_bfloat16* __restrict__ WhT,  // [B][HD][N]
    float* __restrict__ tI,            // [B][H][N]
    float* __restrict__ tJ)            // [B][H][N]
{
    const int row0 = blockIdx.x * 16;    // global row (b*N+n)
    const int b    = row0 >> 10;
    const int n0   = row0 & (N - 1);
    const int t    = threadIdx.x;
    const int lane = t & 63, wave = t >> 6;
    const int mn   = lane & 15, kg = lane >> 4;

    __shared__ __align__(16) __hip_bfloat16 hA[16][136];   // [row][k]
    __shared__ __align__(16) __hip_bfloat16 Wt[128][136];  // [col][k]

    // stage h-tile (16x128 f32 -> bf16)
    {
        const float4* hf = reinterpret_cast<const float4*>(hsrc + (size_t)row0 * DIN);
        #pragma unroll
        for (int u = 0; u < 2; ++u) {
            const int idx = t + u * 256;          // float4 index
            const float4 v = hf[idx];
            const int r = idx >> 5, c4 = (idx & 31) * 4;
            hA[r][c4]     = __float2bfloat16(v.x);
            hA[r][c4 + 1] = __float2bfloat16(v.y);
            hA[r][c4 + 2] = __float2bfloat16(v.z);
            hA[r][c4 + 3] = __float2bfloat16(v.w);
        }
    }
    // stage W transposed (128x128 f32 [k][c] -> bf16 [c][k])
    {
        const float4* wf = reinterpret_cast<const float4*>(W);
        #pragma unroll
        for (int u = 0; u < 16; ++u) {
            const int idx = t + u * 256;
            const float4 v = wf[idx];
            const int k = idx >> 5, c0 = (idx & 31) * 4;
            Wt[c0][k]     = __float2bfloat16(v.x);
            Wt[c0 + 1][k] = __float2bfloat16(v.y);
            Wt[c0 + 2][k] = __float2bfloat16(v.z);
            Wt[c0 + 3][k] = __float2bfloat16(v.w);
        }
    }
    __syncthreads();

    f32x4 acc[2];
    acc[0] = (f32x4){0.f, 0.f, 0.f, 0.f};
    acc[1] = (f32x4){0.f, 0.f, 0.f, 0.f};

    #pragma unroll
    for (int kk = 0; kk < 4; ++kk) {
        const bf16x8 af = *reinterpret_cast<const bf16x8*>(
            &hA[mn][kk * 32 + kg * 8]);
        #pragma unroll
        for (int f = 0; f < 2; ++f) {
            const int F = wave * 2 + f;           // col-frag = head
            const bf16x8 bfr = *reinterpret_cast<const bf16x8*>(
                &Wt[F * 16 + mn][kk * 32 + kg * 8]);
            acc[f] = __builtin_amdgcn_mfma_f32_16x16x32_bf16(af, bfr, acc[f], 0, 0, 0);
        }
    }

    // epilogue: WhT store + tI/tJ shuffle-reduce (head = F, d = mn)
    #pragma unroll
    for (int f = 0; f < 2; ++f) {
        const int F = wave * 2 + f;
        const float as = a[F * 32 + mn];       // a[h][d]
        const float ad = a[F * 32 + 16 + mn];  // a[h][D+d]
        #pragma unroll
        for (int r = 0; r < 4; ++r) {
            const int n = n0 + kg * 4 + r;
            WhT[((size_t)(b * HD + F * 16 + mn)) * N + n] =
                __float2bfloat16(acc[f][r]);
            float vi = acc[f][r] * as;
            float vj = acc[f][r] * ad;
            #pragma unroll
            for (int m = 1; m < 16; m <<= 1) {
                vi += __shfl_xor(vi, m);
                vj += __shfl_xor(vj, m);
            }
            if (mn == 0) {
                tI[((size_t)(b * H + F)) * N + n] = fminf(vi * LOG2E, TCLAMP);
                tJ[((size_t)(b * H + F)) * N + n] = fminf(vj * LOG2E, TCLAMP);
            }
        }
    }
}

// ---------------------------------------------------------------------------
// Kernel 2: fused attention — register ping-pong pipeline with
// sched_barrier(0) pinning (loads of set X+1 cannot sink into compute of X).
// Block = 256 thr = 4 waves = 4 heads; blockIdx.z = head half.
// Lane (mn,kg) owns row i0+mn; builds A-frag scores in registers
// (k = sq*128 + q*32 + kg*8 + e), matching the MFMA A layout.
// accO += P x WhT, accD += P x 1; out = accO/accD (shift-invariant softmax).
// ---------------------------------------------------------------------------

#define LOADSET(M, T0, T1, WV, SQ) do {                                        \
    M = mrow[SQ];                                                              \
    _Pragma("unroll")                                                          \
    for (int q = 0; q < 4; ++q) {                                              \
        T0[q] = *reinterpret_cast<const float4*>(tjrow + (SQ) * 128 + q * 32);     \
        T1[q] = *reinterpret_cast<const float4*>(tjrow + (SQ) * 128 + q * 32 + 4); \
        WV[q] = *reinterpret_cast<const bf16x8*>(wrow + (SQ) * 128 + q * 32);      \
    } } while (0)

#define COMPUTESET(M, T0, T1, WV) do {                                         \
    const unsigned int mq_[4] = {M.x, M.y, M.z, M.w};                          \
    _Pragma("unroll")                                                          \
    for (int q = 0; q < 4; ++q) {                                              \
        const unsigned int m8_ = (mq_[q] >> (kg * 8)) & 0xFFu;                 \
        const float tv_[8] = {T0[q].x, T0[q].y, T0[q].z, T0[q].w,              \
                              T1[q].x, T1[q].y, T1[q].z, T1[q].w};             \
        bf16x8 af_;                                                            \
        _Pragma("unroll")                                                      \
        for (int e = 0; e < 8; ++e) {                                          \
            const float x_ = Arow + tv_[e];                                    \
            float sc_ = fmaxf(x_, 0.2f * x_);                                  \
            sc_ = ((m8_ >> e) & 1u) ? sc_ : -1.0e30f;                          \
            af_[e] = (short)__bfloat16_as_ushort(                              \
                __float2bfloat16(fast_exp2(sc_)));                             \
        }                                                                      \
        accO = __builtin_amdgcn_mfma_f32_16x16x32_bf16(af_, WV[q], accO, 0, 0, 0); \
        accD = __builtin_amdgcn_mfma_f32_16x16x32_bf16(af_, ones, accD, 0, 0, 0);  \
    } } while (0)

__global__ __launch_bounds__(256) void k_attn(
    const unsigned int*   __restrict__ bm,     // [B*N][32] u32
    const __hip_bfloat16* __restrict__ WhT,    // [B][HD][N]
    const float*          __restrict__ tI,     // [B][H][N]
    const float*          __restrict__ tJ,     // [B][H][N]
    float*                __restrict__ out)    // [B][N][HD]
{
    const int b    = blockIdx.y;
    const int i0   = blockIdx.x * TI;
    const int lane = threadIdx.x & 63;
    const int h    = blockIdx.z * 4 + (threadIdx.x >> 6);   // head
    const int mn   = lane & 15, kg = lane >> 4;
    const int row  = i0 + mn;

    const float Arow = tI[((size_t)(b * H + h)) * N + row];
    const float* tjrow = tJ + ((size_t)(b * H + h)) * N + kg * 8;
    const __hip_bfloat16* wrow =
        WhT + ((size_t)(b * HD + h * 16 + mn)) * N + kg * 8;
    const uint4* mrow = reinterpret_cast<const uint4*>(
        bm + ((size_t)(b * N) + row) * 32);

    f32x4 accO = {0.f, 0.f, 0.f, 0.f};
    f32x4 accD = {0.f, 0.f, 0.f, 0.f};
    bf16x8 ones;
    #pragma unroll
    for (int e = 0; e < 8; ++e) ones[e] = (short)0x3F80;   // bf16 1.0

    uint4 mA; float4 taA[4], tbA[4]; bf16x8 wvA[4];
    uint4 mB; float4 taB[4], tbB[4]; bf16x8 wvB[4];

    LOADSET(mA, taA, tbA, wvA, 0);
    #pragma unroll
    for (int s2 = 0; s2 < 4; ++s2) {
        LOADSET(mB, taB, tbB, wvB, 2 * s2 + 1);
        __builtin_amdgcn_sched_barrier(0);     // pin B-loads above A-compute
        COMPUTESET(mA, taA, tbA, wvA);
        if (s2 < 3) {
            LOADSET(mA, taA, tbA, wvA, 2 * s2 + 2);
        }
        __builtin_amdgcn_sched_barrier(0);     // pin A-loads above B-compute
        COMPUTESET(mB, taB, tbB, wvB);
    }

    // ---- normalize + store: C layout col=lane&15, row=(lane>>4)*4+reg ----
    #pragma unroll
    for (int r = 0; r < 4; ++r) {
        out[((size_t)(b * N) + i0 + kg * 4 + r) * HD + h * 16 + mn] =
            accO[r] / accD[r];
    }
}

// ---------------------------------------------------------------------------
extern "C" void kernel_launch(void* const* d_in, const int* in_sizes, int n_in,
                              void* d_out, int out_size, void* d_ws, size_t ws_size,
                              hipStream_t stream)
{
    const float* h   = (const float*)d_in[0];   // f32 (proven R3/R5)
    const int*   adj = (const int*)d_in[1];
    const float* W   = (const float*)d_in[2];
    const float* a   = (const float*)d_in[3];
    float* out = (float*)d_out;

    float* ws = (float*)d_ws;
    float* tI = ws;                              // B*H*N f32 (256 KB)
    float* tJ = ws + (size_t)B * H * N;          // B*H*N f32 (256 KB)
    __hip_bfloat16* WhT = (__hip_bfloat16*)(ws + (size_t)2 * B * H * N); // 2 MB
    unsigned int* bm = (unsigned int*)((char*)WhT +
                       (size_t)B * N * HD * sizeof(__hip_bfloat16));     // 1 MB

    k_pack<<<dim3(B * N / 4), dim3(256), 0, stream>>>(adj, bm);
    k_proj<<<dim3(B * N / 16), dim3(256), 0, stream>>>(h, W, a, WhT, tI, tJ);
    k_attn<<<dim3(N / TI, B, 2), dim3(256), 0, stream>>>(bm, WhT, tI, tJ, out);
}